// Round 15
// baseline (221.763 us; speedup 1.0000x reference)
//
#include <hip/hip_runtime.h>

#define N_NODES 100000
#define N_EDGES 600000
#define DIM 128

#define N4 (N_NODES / 4)
#define SCAN_BLOCKS ((N_NODES + 1023) / 1024)   // 98

// kA partition: hist || tconv(UT) || tconv(IT) || tconv(BT)
#define HIST_B  2344      // ceil(600000/256)
#define TCONV_B 1563      // ceil(100000/64)
// kB partition: XCD-partitioned bucket || combine
#define NPART    8
#define CHUNKS   ((N_EDGES + 1023) / 1024)      // 586
#define BUCKET_B (CHUNKS * NPART)               // 4688
#define COMBINE_B 6250                          // 100000*16/256
#define PART_SZ  (N_NODES / NPART)              // 12500

typedef __attribute__((ext_vector_type(8))) short bf16x8;
typedef __attribute__((ext_vector_type(4))) float f32x4;

__device__ __forceinline__ void fma4(float4& acc, float s, const float4 w) {
    acc.x = fmaf(s, w.x, acc.x);
    acc.y = fmaf(s, w.y, acc.y);
    acc.z = fmaf(s, w.z, acc.z);
    acc.w = fmaf(s, w.w, acc.w);
}

__device__ __forceinline__ unsigned short f2bf(float f) {
    union { float f; unsigned int u; } v; v.f = f;
    unsigned int r = v.u + 0x7fffu + ((v.u >> 16) & 1u);   // RNE
    return (unsigned short)(r >> 16);
}

__device__ __forceinline__ float bf2f(unsigned short u) {
    union { unsigned int i; float f; } v;
    v.i = ((unsigned int)u) << 16;
    return v.f;
}

// Streaming table transform: TW = bf16(T @ W^T), one 64-row tile per call.
// Swapped-operand MFMA (verified R3+): E[i][j] = sum_k W[i][k]*T[r0+j][k];
// C/D: j = lane&15 (out row), i = 16ti + 4*(lane>>4) + q.
// A-frags built directly from W (64KB, L2-resident; same data for all blocks):
// lane l, slot (ti,s): W[16ti + (l&15)][32s + 8*(l>>4) .. +7].
__device__ __forceinline__ void tconv_tile(
    const float* __restrict__ T, unsigned short* __restrict__ TW, int NT,
    const float* __restrict__ W, int base, int t)
{
    int l = t & 63;
    int w = t >> 6;
    int c = l & 15;
    int g = l >> 4;
    int row = base + w * 16 + c;
    int rowc = row < NT ? row : NT - 1;
    const float4* T4 = (const float4*)T;
    const float4* W4 = (const float4*)W;

    bf16x8 bfrag[4];
    #pragma unroll
    for (int s = 0; s < 4; ++s) {
        float4 p0 = T4[(size_t)rowc * 32 + 8 * s + 2 * g];
        float4 p1 = T4[(size_t)rowc * 32 + 8 * s + 2 * g + 1];
        bf16x8 tt;
        tt[0] = (short)f2bf(p0.x); tt[1] = (short)f2bf(p0.y);
        tt[2] = (short)f2bf(p0.z); tt[3] = (short)f2bf(p0.w);
        tt[4] = (short)f2bf(p1.x); tt[5] = (short)f2bf(p1.y);
        tt[6] = (short)f2bf(p1.z); tt[7] = (short)f2bf(p1.w);
        bfrag[s] = tt;
    }

    f32x4 acc[8];
    #pragma unroll
    for (int ti = 0; ti < 8; ++ti) acc[ti] = (f32x4){0.f, 0.f, 0.f, 0.f};

    #pragma unroll
    for (int ti = 0; ti < 8; ++ti) {
        int wrow = 16 * ti + c;
        #pragma unroll
        for (int s = 0; s < 4; ++s) {
            float4 w0 = W4[wrow * 32 + 8 * s + 2 * g];
            float4 w1 = W4[wrow * 32 + 8 * s + 2 * g + 1];
            bf16x8 af;
            af[0] = (short)f2bf(w0.x); af[1] = (short)f2bf(w0.y);
            af[2] = (short)f2bf(w0.z); af[3] = (short)f2bf(w0.w);
            af[4] = (short)f2bf(w1.x); af[5] = (short)f2bf(w1.y);
            af[6] = (short)f2bf(w1.z); af[7] = (short)f2bf(w1.w);
            acc[ti] = __builtin_amdgcn_mfma_f32_16x16x32_bf16(af, bfrag[s], acc[ti], 0, 0, 0);
        }
    }

    if (row < NT) {
        unsigned short* yr = TW + (size_t)row * DIM;
        #pragma unroll
        for (int ti = 0; ti < 8; ++ti) {
            ushort4 o;
            o.x = f2bf(acc[ti][0]);
            o.y = f2bf(acc[ti][1]);
            o.z = f2bf(acc[ti][2]);
            o.w = f2bf(acc[ti][3]);
            *(ushort4*)(yr + 16 * ti + 4 * g) = o;
        }
    }
}

// ---------------- kA: hist || tconv(UT) || tconv(IT) || tconv(BT) ----------------
__global__ __launch_bounds__(256) void ka_kernel(
    const int* __restrict__ rows, int* __restrict__ cnt,
    const float* __restrict__ ut, const float* __restrict__ itb, const float* __restrict__ bt,
    const float* __restrict__ W,
    unsigned short* __restrict__ utw, unsigned short* __restrict__ itw,
    unsigned short* __restrict__ btw)
{
    int b = blockIdx.x;
    int t = threadIdx.x;
    if (b < HIST_B) {
        int e = b * 256 + t;
        if (e < N_EDGES) atomicAdd(&cnt[rows[e]], 1);
    } else if (b < HIST_B + TCONV_B) {
        tconv_tile(ut, utw, N_NODES, W, (b - HIST_B) * 64, t);
    } else if (b < HIST_B + 2 * TCONV_B) {
        tconv_tile(itb, itw, N_NODES, W, (b - HIST_B - TCONV_B) * 64, t);
    } else {
        tconv_tile(bt, btw, 4, W, 0, t);
    }
}

// scan level 1
__global__ __launch_bounds__(256) void scan1_kernel(
    const int* __restrict__ cnt, int* __restrict__ off, int* __restrict__ bsum)
{
    __shared__ int s[256];
    int t = threadIdx.x;
    int b = blockIdx.x;
    int i4 = b * 256 + t;
    int4 c = {0, 0, 0, 0};
    if (i4 < N4) c = ((const int4*)cnt)[i4];
    int tsum = c.x + c.y + c.z + c.w;
    s[t] = tsum;
    __syncthreads();
    for (int d = 1; d < 256; d <<= 1) {
        int v = (t >= d) ? s[t - d] : 0;
        __syncthreads();
        s[t] += v;
        __syncthreads();
    }
    int texcl = s[t] - tsum;
    if (t == 255) bsum[b] = s[255];
    if (i4 < N4) {
        int4 o;
        o.x = texcl;
        o.y = o.x + c.x;
        o.z = o.y + c.y;
        o.w = o.z + c.z;
        ((int4*)off)[i4] = o;
    }
}

// scan level 2+3
__global__ __launch_bounds__(256) void scan3_kernel(
    const int* __restrict__ bsum, int* __restrict__ off, int* __restrict__ cur)
{
    __shared__ int s[256];
    int t = threadIdx.x;
    int b = blockIdx.x;
    s[t] = (t < b && t < SCAN_BLOCKS) ? bsum[t] : 0;
    __syncthreads();
    for (int d = 1; d < 256; d <<= 1) {
        int v = (t >= d) ? s[t - d] : 0;
        __syncthreads();
        s[t] += v;
        __syncthreads();
    }
    int base = s[255];
    int i4 = b * 256 + t;
    if (i4 < N4) {
        int4 o = ((const int4*)off)[i4];
        o.x += base; o.y += base; o.z += base; o.w += base;
        ((int4*)off)[i4] = o;
        ((int4*)cur)[i4] = o;
    }
    if (b == 0 && t == 0) off[N_NODES] = N_EDGES;
}

// ---------------- kB: XCD-partitioned bucket || combine ----------------
// Bucket (R14-verified): block b handles edge-chunk b>>3, scatters only rows
// in partition b&7 -> all writers of an epack line on one XCD, L2 merges.
// Combine: y[r] = bf16(UTW[user[r]] + ITW[item[r]] + BTW[behavior[r]]),
// 16 lanes/row, 16B bf16 gathers from the cache-hot transformed tables.
__global__ __launch_bounds__(256) void kb_kernel(
    const int* __restrict__ rows, const int* __restrict__ cols, const float* __restrict__ vals,
    int* __restrict__ cur, int2* __restrict__ epack,
    const int* __restrict__ user, const int* __restrict__ item, const int* __restrict__ behavior,
    const unsigned short* __restrict__ utw, const unsigned short* __restrict__ itw,
    const unsigned short* __restrict__ btw, unsigned short* __restrict__ y)
{
    int b = blockIdx.x;
    int t = threadIdx.x;
    if (b < BUCKET_B) {
        int p = b & (NPART - 1);
        int chunk = b >> 3;
        int base = chunk * 1024;
        #pragma unroll
        for (int j = 0; j < 4; ++j) {
            int e = base + t + j * 256;
            if (e < N_EDGES) {
                int r = rows[e];
                if (r / PART_SZ == p) {
                    int slot = atomicAdd(&cur[r], 1);
                    int2 pk;
                    pk.x = cols[e];
                    pk.y = __float_as_int(vals[e]);
                    epack[slot] = pk;
                }
            }
        }
    } else {
        int gid = (b - BUCKET_B) * 256 + t;
        int r = gid >> 4;
        int m = gid & 15;
        if (r < N_NODES) {
            int u  = user[r];
            int iv = item[r];
            int bh = behavior[r];
            const bf16x8* U8 = (const bf16x8*)utw;
            const bf16x8* I8 = (const bf16x8*)itw;
            const bf16x8* B8 = (const bf16x8*)btw;
            bf16x8 au = U8[(size_t)u  * 16 + m];
            bf16x8 ai = I8[(size_t)iv * 16 + m];
            bf16x8 ab = B8[bh * 16 + m];
            bf16x8 o;
            #pragma unroll
            for (int j = 0; j < 8; ++j) {
                float f = bf2f((unsigned short)au[j]) + bf2f((unsigned short)ai[j])
                        + bf2f((unsigned short)ab[j]);
                o[j] = (short)f2bf(f);
            }
            ((bf16x8*)y)[(size_t)r * 16 + m] = o;
        }
    }
}

// agg: out[r] = b + sum_{e in row r} val[e] * y[col[e]]   (y bf16, acc f32)
__global__ __launch_bounds__(256) void agg_bias_kernel(
    const int* __restrict__ off, const int2* __restrict__ epack,
    const unsigned short* __restrict__ y, const float* __restrict__ bias,
    float* __restrict__ out)
{
    int gid = blockIdx.x * 256 + threadIdx.x;
    int r = gid >> 4;
    int m = gid & 15;
    if (r >= N_NODES) return;
    int s = off[r], e = off[r + 1];
    const bf16x8* y8 = (const bf16x8*)y;   // index = node*16 + m

    float a0[8], a1[8], a2[8], a3[8];
    #pragma unroll
    for (int j = 0; j < 8; ++j) { a0[j] = 0.f; a1[j] = 0.f; a2[j] = 0.f; a3[j] = 0.f; }

    int i = s;
    for (; i + 3 < e; i += 4) {
        int2 p0 = epack[i];
        int2 p1 = epack[i + 1];
        int2 p2 = epack[i + 2];
        int2 p3 = epack[i + 3];
        bf16x8 y0 = y8[(size_t)p0.x * 16 + m];
        bf16x8 y1 = y8[(size_t)p1.x * 16 + m];
        bf16x8 y2 = y8[(size_t)p2.x * 16 + m];
        bf16x8 y3 = y8[(size_t)p3.x * 16 + m];
        float v0 = __int_as_float(p0.y);
        float v1 = __int_as_float(p1.y);
        float v2 = __int_as_float(p2.y);
        float v3 = __int_as_float(p3.y);
        #pragma unroll
        for (int j = 0; j < 8; ++j) {
            a0[j] = fmaf(v0, bf2f((unsigned short)y0[j]), a0[j]);
            a1[j] = fmaf(v1, bf2f((unsigned short)y1[j]), a1[j]);
            a2[j] = fmaf(v2, bf2f((unsigned short)y2[j]), a2[j]);
            a3[j] = fmaf(v3, bf2f((unsigned short)y3[j]), a3[j]);
        }
    }
    for (; i < e; ++i) {
        int2 p0 = epack[i];
        float v0 = __int_as_float(p0.y);
        bf16x8 y0 = y8[(size_t)p0.x * 16 + m];
        #pragma unroll
        for (int j = 0; j < 8; ++j)
            a0[j] = fmaf(v0, bf2f((unsigned short)y0[j]), a0[j]);
    }

    const float4* b4 = (const float4*)bias;
    float4 bb0 = b4[2 * m], bb1 = b4[2 * m + 1];
    float4 o0, o1;
    o0.x = a0[0] + a1[0] + a2[0] + a3[0] + bb0.x;
    o0.y = a0[1] + a1[1] + a2[1] + a3[1] + bb0.y;
    o0.z = a0[2] + a1[2] + a2[2] + a3[2] + bb0.z;
    o0.w = a0[3] + a1[3] + a2[3] + a3[3] + bb0.w;
    o1.x = a0[4] + a1[4] + a2[4] + a3[4] + bb1.x;
    o1.y = a0[5] + a1[5] + a2[5] + a3[5] + bb1.y;
    o1.z = a0[6] + a1[6] + a2[6] + a3[6] + bb1.z;
    o1.w = a0[7] + a1[7] + a2[7] + a3[7] + bb1.w;
    float4* orow = (float4*)(out + (size_t)r * DIM);
    orow[2 * m]     = o0;
    orow[2 * m + 1] = o1;
}

// ---- fallback path kernels (mid / tiny ws) ----

__global__ __launch_bounds__(256) void hist_kernel(
    const int* __restrict__ rows, int* __restrict__ cnt)
{
    int e = blockIdx.x * 256 + threadIdx.x;
    if (e >= N_EDGES) return;
    atomicAdd(&cnt[rows[e]], 1);
}

__global__ __launch_bounds__(256) void bucket_kernel(
    const int* __restrict__ rows, const int* __restrict__ cols, const float* __restrict__ vals,
    int* __restrict__ cur, int2* __restrict__ epack)
{
    int e = blockIdx.x * 256 + threadIdx.x;
    if (e >= N_EDGES) return;
    int r = rows[e];
    int slot = atomicAdd(&cur[r], 1);
    int2 p;
    p.x = cols[e];
    p.y = __float_as_int(vals[e]);
    epack[slot] = p;
}

__global__ __launch_bounds__(256) void agg_fused_kernel(
    const int* __restrict__ off, const int2* __restrict__ epack,
    const int* __restrict__ user, const int* __restrict__ item, const int* __restrict__ behavior,
    const float* __restrict__ ut, const float* __restrict__ itb, const float* __restrict__ bt,
    float* __restrict__ out)
{
    int gid = blockIdx.x * 256 + threadIdx.x;
    int r = gid >> 5;
    int m = gid & 31;
    if (r >= N_NODES) return;
    int s = off[r], e = off[r + 1];
    const float4* ut4 = (const float4*)ut;
    const float4* it4 = (const float4*)itb;
    const float4* bt4 = (const float4*)bt;
    float4 acc = {0.f, 0.f, 0.f, 0.f};
    for (int i = s; i < e; ++i) {
        int2 p = epack[i];
        int c = p.x;
        float v = __int_as_float(p.y);
        float4 a = ut4[(size_t)user[c] * 32 + m];
        float4 cc = it4[(size_t)item[c] * 32 + m];
        float4 d = bt4[(size_t)behavior[c] * 32 + m];
        a.x += cc.x + d.x; a.y += cc.y + d.y; a.z += cc.z + d.z; a.w += cc.w + d.w;
        fma4(acc, v, a);
    }
    ((float4*)out)[(size_t)r * 32 + m] = acc;
}

__global__ __launch_bounds__(256) void scatter_fused_kernel(
    const int* __restrict__ rows, const int* __restrict__ cols, const float* __restrict__ vals,
    const int* __restrict__ user, const int* __restrict__ item, const int* __restrict__ behavior,
    const float* __restrict__ ut, const float* __restrict__ itb, const float* __restrict__ bt,
    float* __restrict__ agg)
{
    int wave = (blockIdx.x * 256 + threadIdx.x) >> 6;
    int lane = threadIdx.x & 63;
    int e = wave * 2 + (lane >> 5);
    if (e >= N_EDGES) return;
    int r = rows[e];
    int c = cols[e];
    float v = vals[e];
    int m = lane & 31;
    const float4* ut4 = (const float4*)ut;
    const float4* it4 = (const float4*)itb;
    const float4* bt4 = (const float4*)bt;
    float4 a = ut4[(size_t)user[c] * 32 + m];
    float4 cc = it4[(size_t)item[c] * 32 + m];
    float4 d = bt4[(size_t)behavior[c] * 32 + m];
    a.x += cc.x + d.x; a.y += cc.y + d.y; a.z += cc.z + d.z; a.w += cc.w + d.w;
    float* o = agg + (size_t)r * DIM + m * 4;
    atomicAdd(o + 0, v * a.x);
    atomicAdd(o + 1, v * a.y);
    atomicAdd(o + 2, v * a.z);
    atomicAdd(o + 3, v * a.w);
}

// fallback GEMM: out[r] = agg[r] @ W^T + b, in-place f32 on io (verified R3)
__global__ __launch_bounds__(256) void gemm_mfma_kernel(
    const float* __restrict__ W, const float* __restrict__ bias, float* io)
{
    __shared__ unsigned short wlds[128 * 128];

    int tid = threadIdx.x;
    for (int c4 = tid; c4 < 128 * 128 / 4; c4 += 256) {
        float4 wv = ((const float4*)W)[c4];
        int i  = c4 >> 5;
        int k0 = (c4 & 31) * 4;
        int slot = (i >> 4) * 4 + (k0 >> 5);
        int lane = ((k0 & 31) >> 3) * 16 + (i & 15);
        ushort4 o;
        o.x = f2bf(wv.x); o.y = f2bf(wv.y); o.z = f2bf(wv.z); o.w = f2bf(wv.w);
        *(ushort4*)&wlds[slot * 512 + lane * 8 + (k0 & 7)] = o;
    }
    __syncthreads();

    int l = tid & 63;
    int w = tid >> 6;
    int c = l & 15;
    int g = l >> 4;
    int row = blockIdx.x * 64 + w * 16 + c;
    int rowc = row < N_NODES ? row : N_NODES - 1;

    const float4* a4 = (const float4*)io;
    bf16x8 bfrag[4];
    #pragma unroll
    for (int s = 0; s < 4; ++s) {
        float4 p0 = a4[(size_t)rowc * 32 + 8 * s + 2 * g];
        float4 p1 = a4[(size_t)rowc * 32 + 8 * s + 2 * g + 1];
        bf16x8 t;
        t[0] = (short)f2bf(p0.x); t[1] = (short)f2bf(p0.y);
        t[2] = (short)f2bf(p0.z); t[3] = (short)f2bf(p0.w);
        t[4] = (short)f2bf(p1.x); t[5] = (short)f2bf(p1.y);
        t[6] = (short)f2bf(p1.z); t[7] = (short)f2bf(p1.w);
        bfrag[s] = t;
    }

    f32x4 acc[8];
    #pragma unroll
    for (int ti = 0; ti < 8; ++ti) acc[ti] = (f32x4){0.f, 0.f, 0.f, 0.f};

    const bf16x8* wf = (const bf16x8*)wlds;
    #pragma unroll
    for (int ti = 0; ti < 8; ++ti) {
        #pragma unroll
        for (int s = 0; s < 4; ++s) {
            bf16x8 af = wf[(ti * 4 + s) * 64 + l];
            acc[ti] = __builtin_amdgcn_mfma_f32_16x16x32_bf16(af, bfrag[s], acc[ti], 0, 0, 0);
        }
    }

    if (row < N_NODES) {
        float4* orow = (float4*)(io + (size_t)row * DIM);
        const float4* b4 = (const float4*)bias;
        #pragma unroll
        for (int ti = 0; ti < 8; ++ti) {
            float4 bb = b4[ti * 4 + g];
            float4 o;
            o.x = acc[ti][0] + bb.x;
            o.y = acc[ti][1] + bb.y;
            o.z = acc[ti][2] + bb.z;
            o.w = acc[ti][3] + bb.w;
            orow[ti * 4 + g] = o;
        }
    }
}

extern "C" void kernel_launch(void* const* d_in, const int* in_sizes, int n_in,
                              void* d_out, int out_size, void* d_ws, size_t ws_size,
                              hipStream_t stream) {
    const int*   user           = (const int*)d_in[0];
    const int*   item           = (const int*)d_in[1];
    const int*   behavior       = (const int*)d_in[2];
    const int*   adj_rows       = (const int*)d_in[3];
    const int*   adj_cols       = (const int*)d_in[4];
    const float* adj_vals       = (const float*)d_in[5];
    const float* user_table     = (const float*)d_in[6];
    const float* item_table     = (const float*)d_in[7];
    const float* behavior_table = (const float*)d_in[8];
    const float* W              = (const float*)d_in[9];
    const float* b              = (const float*)d_in[10];
    float* out = (float*)d_out;

    const size_t TW_BYTES    = (size_t)N_NODES * DIM * sizeof(unsigned short); // 25,600,000
    const size_t Y_BYTES     = TW_BYTES;                                       // 25,600,000
    const size_t CNT_BYTES   = (size_t)N_NODES * sizeof(int);                  // 400,000
    const size_t OFF_BYTES   = ((size_t)(N_NODES + 1) * sizeof(int) + 15) & ~(size_t)15;
    const size_t EPACK_BYTES = (size_t)N_EDGES * sizeof(int2);                 // 4,800,000
    const size_t BTW_BYTES   = 1024;

    const int edge_blocks = (N_EDGES + 255) / 256;
    const int agg_blocks  = (N_NODES * 16 + 255) / 256;  // 6250
    const int gemm_blocks = (N_NODES + 63) / 64;         // 1563 (fallback)

    char* ws = (char*)d_ws;
    const size_t need_full = Y_BYTES + CNT_BYTES + OFF_BYTES + EPACK_BYTES + BTW_BYTES;
    const size_t need_csr  = CNT_BYTES + OFF_BYTES + EPACK_BYTES;

    if (ws_size >= need_full) {
        // UTW/ITW live in d_out (dead until agg fully overwrites it)
        unsigned short* utw = (unsigned short*)d_out;
        unsigned short* itw = utw + (size_t)N_NODES * DIM;
        size_t o = 0;
        unsigned short* y = (unsigned short*)(ws + o); o += Y_BYTES;
        int*  cnt   = (int*)(ws + o); o += CNT_BYTES;    // then fine cursor
        int*  off   = (int*)(ws + o); o += OFF_BYTES;
        int2* epack = (int2*)(ws + o); o += EPACK_BYTES;
        unsigned short* btw = (unsigned short*)(ws + o);
        int*  bsum  = (int*)epack;   // epack[0..97] dead until kB-bucket; stream-ordered

        hipMemsetAsync(cnt, 0, CNT_BYTES, stream);
        ka_kernel<<<HIST_B + 2 * TCONV_B + 1, 256, 0, stream>>>(
            adj_rows, cnt, user_table, item_table, behavior_table, W, utw, itw, btw);
        scan1_kernel<<<SCAN_BLOCKS, 256, 0, stream>>>(cnt, off, bsum);
        scan3_kernel<<<SCAN_BLOCKS, 256, 0, stream>>>(bsum, off, cnt);
        kb_kernel<<<BUCKET_B + COMBINE_B, 256, 0, stream>>>(
            adj_rows, adj_cols, adj_vals, cnt, epack,
            user, item, behavior, utw, itw, btw, y);
        agg_bias_kernel<<<agg_blocks, 256, 0, stream>>>(off, epack, y, b, out);
    } else if (ws_size >= need_csr) {
        int*  cnt   = (int*)ws;
        int*  off   = (int*)(ws + CNT_BYTES);
        int2* epack = (int2*)(ws + CNT_BYTES + OFF_BYTES);
        int*  bsum  = (int*)epack;

        hipMemsetAsync(cnt, 0, CNT_BYTES, stream);
        hist_kernel<<<edge_blocks, 256, 0, stream>>>(adj_rows, cnt);
        scan1_kernel<<<SCAN_BLOCKS, 256, 0, stream>>>(cnt, off, bsum);
        scan3_kernel<<<SCAN_BLOCKS, 256, 0, stream>>>(bsum, off, cnt);
        bucket_kernel<<<edge_blocks, 256, 0, stream>>>(
            adj_rows, adj_cols, adj_vals, cnt, epack);
        agg_fused_kernel<<<(N_NODES * 32 + 255) / 256, 256, 0, stream>>>(
            off, epack, user, item, behavior,
            user_table, item_table, behavior_table, out);
        gemm_mfma_kernel<<<gemm_blocks, 256, 0, stream>>>(W, b, out);
    } else {
        hipMemsetAsync(d_out, 0, (size_t)N_NODES * DIM * sizeof(float), stream);
        const int scatter_blocks = (N_EDGES / 2 * 64 + 255) / 256;
        scatter_fused_kernel<<<scatter_blocks, 256, 0, stream>>>(
            adj_rows, adj_cols, adj_vals, user, item, behavior,
            user_table, item_table, behavior_table, out);
        gemm_mfma_kernel<<<gemm_blocks, 256, 0, stream>>>(W, b, out);
    }
}

// Round 16
// 150.626 us; speedup vs baseline: 1.4723x; 1.4723x over previous
//
#include <hip/hip_runtime.h>

#define N_NODES 100000
#define N_EDGES 600000
#define DIM 128

#define N4 (N_NODES / 4)
#define SCAN_BLOCKS ((N_NODES + 1023) / 1024)   // 98

// kA partition: tconv(UT) || tconv(IT) || tconv(BT) || hist
#define TCONV_B 1563      // ceil(100000/64)
#define HIST_B  2344      // ceil(600000/256)
// kB partition: XCD-partitioned bucket || combine
#define NPART    8
#define CHUNKS   ((N_EDGES + 1023) / 1024)      // 586
#define BUCKET_B (CHUNKS * NPART)               // 4688
#define COMBINE_B 6250                          // 100000*16/256
#define PART_SZ  (N_NODES / NPART)              // 12500

typedef __attribute__((ext_vector_type(8))) short bf16x8;
typedef __attribute__((ext_vector_type(4))) float f32x4;

__device__ __forceinline__ void fma4(float4& acc, float s, const float4 w) {
    acc.x = fmaf(s, w.x, acc.x);
    acc.y = fmaf(s, w.y, acc.y);
    acc.z = fmaf(s, w.z, acc.z);
    acc.w = fmaf(s, w.w, acc.w);
}

__device__ __forceinline__ unsigned short f2bf(float f) {
    union { float f; unsigned int u; } v; v.f = f;
    unsigned int r = v.u + 0x7fffu + ((v.u >> 16) & 1u);   // RNE
    return (unsigned short)(r >> 16);
}

__device__ __forceinline__ float bf2f(unsigned short u) {
    union { unsigned int i; float f; } v;
    v.i = ((unsigned int)u) << 16;
    return v.f;
}

// W pre-conversion: f32 row-major [i][k] -> bf16 fragment-ordered wfrag (32KB).
// slot = (i>>4)*4 + (k0>>5); lane = ((k0&31)>>3)*16 + (i&15); elem u = k0&7.
__global__ __launch_bounds__(256) void wconv_kernel(
    const float* __restrict__ W, unsigned short* __restrict__ wfrag)
{
    int c4 = blockIdx.x * 256 + threadIdx.x;
    if (c4 >= 128 * 128 / 4) return;
    float4 wv = ((const float4*)W)[c4];
    int i  = c4 >> 5;
    int k0 = (c4 & 31) * 4;
    int slot = (i >> 4) * 4 + (k0 >> 5);
    int lane = ((k0 & 31) >> 3) * 16 + (i & 15);
    ushort4 o;
    o.x = f2bf(wv.x); o.y = f2bf(wv.y); o.z = f2bf(wv.z); o.w = f2bf(wv.w);
    *(ushort4*)&wfrag[slot * 512 + lane * 8 + (k0 & 7)] = o;
}

// Streaming table transform: TW = bf16(T @ W^T), one 64-row tile per call.
// A-fragments from PRE-CONVERTED wfrag (32KB bf16, L1-resident — R7/R13
// verified pattern); bfrag from T via coalesced f32 streaming reads.
// Swapped-operand MFMA: C/D j = lane&15 (out row), i = 16ti + 4*(lane>>4) + q.
__device__ __forceinline__ void tconv_tile(
    const float* __restrict__ T, unsigned short* __restrict__ TW, int NT,
    const bf16x8* __restrict__ wf, int base, int t)
{
    int l = t & 63;
    int w = t >> 6;
    int c = l & 15;
    int g = l >> 4;
    int row = base + w * 16 + c;
    int rowc = row < NT ? row : NT - 1;
    const float4* T4 = (const float4*)T;

    bf16x8 bfrag[4];
    #pragma unroll
    for (int s = 0; s < 4; ++s) {
        float4 p0 = T4[(size_t)rowc * 32 + 8 * s + 2 * g];
        float4 p1 = T4[(size_t)rowc * 32 + 8 * s + 2 * g + 1];
        bf16x8 tt;
        tt[0] = (short)f2bf(p0.x); tt[1] = (short)f2bf(p0.y);
        tt[2] = (short)f2bf(p0.z); tt[3] = (short)f2bf(p0.w);
        tt[4] = (short)f2bf(p1.x); tt[5] = (short)f2bf(p1.y);
        tt[6] = (short)f2bf(p1.z); tt[7] = (short)f2bf(p1.w);
        bfrag[s] = tt;
    }

    f32x4 acc[8];
    #pragma unroll
    for (int ti = 0; ti < 8; ++ti) acc[ti] = (f32x4){0.f, 0.f, 0.f, 0.f};

    #pragma unroll
    for (int ti = 0; ti < 8; ++ti) {
        #pragma unroll
        for (int s = 0; s < 4; ++s) {
            bf16x8 af = wf[(ti * 4 + s) * 64 + l];
            acc[ti] = __builtin_amdgcn_mfma_f32_16x16x32_bf16(af, bfrag[s], acc[ti], 0, 0, 0);
        }
    }

    if (row < NT) {
        unsigned short* yr = TW + (size_t)row * DIM;
        #pragma unroll
        for (int ti = 0; ti < 8; ++ti) {
            ushort4 o;
            o.x = f2bf(acc[ti][0]);
            o.y = f2bf(acc[ti][1]);
            o.z = f2bf(acc[ti][2]);
            o.w = f2bf(acc[ti][3]);
            *(ushort4*)(yr + 16 * ti + 4 * g) = o;
        }
    }
}

// ---------------- kA: tconv(UT) || tconv(IT) || tconv(BT) || hist ----------------
__global__ __launch_bounds__(256) void ka_kernel(
    const int* __restrict__ rows, int* __restrict__ cnt,
    const float* __restrict__ ut, const float* __restrict__ itb, const float* __restrict__ bt,
    const bf16x8* __restrict__ wf,
    unsigned short* __restrict__ utw, unsigned short* __restrict__ itw,
    unsigned short* __restrict__ btw)
{
    int b = blockIdx.x;
    int t = threadIdx.x;
    if (b < TCONV_B) {
        tconv_tile(ut, utw, N_NODES, wf, b * 64, t);
    } else if (b < 2 * TCONV_B) {
        tconv_tile(itb, itw, N_NODES, wf, (b - TCONV_B) * 64, t);
    } else if (b < 2 * TCONV_B + 1) {
        tconv_tile(bt, btw, 4, wf, 0, t);
    } else {
        int e = (b - 2 * TCONV_B - 1) * 256 + t;
        if (e < N_EDGES) atomicAdd(&cnt[rows[e]], 1);
    }
}

// scan level 1
__global__ __launch_bounds__(256) void scan1_kernel(
    const int* __restrict__ cnt, int* __restrict__ off, int* __restrict__ bsum)
{
    __shared__ int s[256];
    int t = threadIdx.x;
    int b = blockIdx.x;
    int i4 = b * 256 + t;
    int4 c = {0, 0, 0, 0};
    if (i4 < N4) c = ((const int4*)cnt)[i4];
    int tsum = c.x + c.y + c.z + c.w;
    s[t] = tsum;
    __syncthreads();
    for (int d = 1; d < 256; d <<= 1) {
        int v = (t >= d) ? s[t - d] : 0;
        __syncthreads();
        s[t] += v;
        __syncthreads();
    }
    int texcl = s[t] - tsum;
    if (t == 255) bsum[b] = s[255];
    if (i4 < N4) {
        int4 o;
        o.x = texcl;
        o.y = o.x + c.x;
        o.z = o.y + c.y;
        o.w = o.z + c.z;
        ((int4*)off)[i4] = o;
    }
}

// scan level 2+3
__global__ __launch_bounds__(256) void scan3_kernel(
    const int* __restrict__ bsum, int* __restrict__ off, int* __restrict__ cur)
{
    __shared__ int s[256];
    int t = threadIdx.x;
    int b = blockIdx.x;
    s[t] = (t < b && t < SCAN_BLOCKS) ? bsum[t] : 0;
    __syncthreads();
    for (int d = 1; d < 256; d <<= 1) {
        int v = (t >= d) ? s[t - d] : 0;
        __syncthreads();
        s[t] += v;
        __syncthreads();
    }
    int base = s[255];
    int i4 = b * 256 + t;
    if (i4 < N4) {
        int4 o = ((const int4*)off)[i4];
        o.x += base; o.y += base; o.z += base; o.w += base;
        ((int4*)off)[i4] = o;
        ((int4*)cur)[i4] = o;
    }
    if (b == 0 && t == 0) off[N_NODES] = N_EDGES;
}

// ---------------- kB: XCD-partitioned bucket || combine ----------------
__global__ __launch_bounds__(256) void kb_kernel(
    const int* __restrict__ rows, const int* __restrict__ cols, const float* __restrict__ vals,
    int* __restrict__ cur, int2* __restrict__ epack,
    const int* __restrict__ user, const int* __restrict__ item, const int* __restrict__ behavior,
    const unsigned short* __restrict__ utw, const unsigned short* __restrict__ itw,
    const unsigned short* __restrict__ btw, unsigned short* __restrict__ y)
{
    int b = blockIdx.x;
    int t = threadIdx.x;
    if (b < BUCKET_B) {
        int p = b & (NPART - 1);
        int chunk = b >> 3;
        int base = chunk * 1024;
        #pragma unroll
        for (int j = 0; j < 4; ++j) {
            int e = base + t + j * 256;
            if (e < N_EDGES) {
                int r = rows[e];
                if (r / PART_SZ == p) {
                    int slot = atomicAdd(&cur[r], 1);
                    int2 pk;
                    pk.x = cols[e];
                    pk.y = __float_as_int(vals[e]);
                    epack[slot] = pk;
                }
            }
        }
    } else {
        int gid = (b - BUCKET_B) * 256 + t;
        int r = gid >> 4;
        int m = gid & 15;
        if (r < N_NODES) {
            int u  = user[r];
            int iv = item[r];
            int bh = behavior[r];
            const bf16x8* U8 = (const bf16x8*)utw;
            const bf16x8* I8 = (const bf16x8*)itw;
            const bf16x8* B8 = (const bf16x8*)btw;
            bf16x8 au = U8[(size_t)u  * 16 + m];
            bf16x8 ai = I8[(size_t)iv * 16 + m];
            bf16x8 ab = B8[bh * 16 + m];
            bf16x8 o;
            #pragma unroll
            for (int j = 0; j < 8; ++j) {
                float f = bf2f((unsigned short)au[j]) + bf2f((unsigned short)ai[j])
                        + bf2f((unsigned short)ab[j]);
                o[j] = (short)f2bf(f);
            }
            ((bf16x8*)y)[(size_t)r * 16 + m] = o;
        }
    }
}

// agg: out[r] = b + sum_{e in row r} val[e] * y[col[e]]   (y bf16, acc f32)
__global__ __launch_bounds__(256) void agg_bias_kernel(
    const int* __restrict__ off, const int2* __restrict__ epack,
    const unsigned short* __restrict__ y, const float* __restrict__ bias,
    float* __restrict__ out)
{
    int gid = blockIdx.x * 256 + threadIdx.x;
    int r = gid >> 4;
    int m = gid & 15;
    if (r >= N_NODES) return;
    int s = off[r], e = off[r + 1];
    const bf16x8* y8 = (const bf16x8*)y;

    float a0[8], a1[8], a2[8], a3[8];
    #pragma unroll
    for (int j = 0; j < 8; ++j) { a0[j] = 0.f; a1[j] = 0.f; a2[j] = 0.f; a3[j] = 0.f; }

    int i = s;
    for (; i + 3 < e; i += 4) {
        int2 p0 = epack[i];
        int2 p1 = epack[i + 1];
        int2 p2 = epack[i + 2];
        int2 p3 = epack[i + 3];
        bf16x8 y0 = y8[(size_t)p0.x * 16 + m];
        bf16x8 y1 = y8[(size_t)p1.x * 16 + m];
        bf16x8 y2 = y8[(size_t)p2.x * 16 + m];
        bf16x8 y3 = y8[(size_t)p3.x * 16 + m];
        float v0 = __int_as_float(p0.y);
        float v1 = __int_as_float(p1.y);
        float v2 = __int_as_float(p2.y);
        float v3 = __int_as_float(p3.y);
        #pragma unroll
        for (int j = 0; j < 8; ++j) {
            a0[j] = fmaf(v0, bf2f((unsigned short)y0[j]), a0[j]);
            a1[j] = fmaf(v1, bf2f((unsigned short)y1[j]), a1[j]);
            a2[j] = fmaf(v2, bf2f((unsigned short)y2[j]), a2[j]);
            a3[j] = fmaf(v3, bf2f((unsigned short)y3[j]), a3[j]);
        }
    }
    for (; i < e; ++i) {
        int2 p0 = epack[i];
        float v0 = __int_as_float(p0.y);
        bf16x8 y0 = y8[(size_t)p0.x * 16 + m];
        #pragma unroll
        for (int j = 0; j < 8; ++j)
            a0[j] = fmaf(v0, bf2f((unsigned short)y0[j]), a0[j]);
    }

    const float4* b4 = (const float4*)bias;
    float4 bb0 = b4[2 * m], bb1 = b4[2 * m + 1];
    float4 o0, o1;
    o0.x = a0[0] + a1[0] + a2[0] + a3[0] + bb0.x;
    o0.y = a0[1] + a1[1] + a2[1] + a3[1] + bb0.y;
    o0.z = a0[2] + a1[2] + a2[2] + a3[2] + bb0.z;
    o0.w = a0[3] + a1[3] + a2[3] + a3[3] + bb0.w;
    o1.x = a0[4] + a1[4] + a2[4] + a3[4] + bb1.x;
    o1.y = a0[5] + a1[5] + a2[5] + a3[5] + bb1.y;
    o1.z = a0[6] + a1[6] + a2[6] + a3[6] + bb1.z;
    o1.w = a0[7] + a1[7] + a2[7] + a3[7] + bb1.w;
    float4* orow = (float4*)(out + (size_t)r * DIM);
    orow[2 * m]     = o0;
    orow[2 * m + 1] = o1;
}

// ---- fallback path kernels (mid / tiny ws) ----

__global__ __launch_bounds__(256) void hist_kernel(
    const int* __restrict__ rows, int* __restrict__ cnt)
{
    int e = blockIdx.x * 256 + threadIdx.x;
    if (e >= N_EDGES) return;
    atomicAdd(&cnt[rows[e]], 1);
}

__global__ __launch_bounds__(256) void bucket_kernel(
    const int* __restrict__ rows, const int* __restrict__ cols, const float* __restrict__ vals,
    int* __restrict__ cur, int2* __restrict__ epack)
{
    int e = blockIdx.x * 256 + threadIdx.x;
    if (e >= N_EDGES) return;
    int r = rows[e];
    int slot = atomicAdd(&cur[r], 1);
    int2 p;
    p.x = cols[e];
    p.y = __float_as_int(vals[e]);
    epack[slot] = p;
}

__global__ __launch_bounds__(256) void agg_fused_kernel(
    const int* __restrict__ off, const int2* __restrict__ epack,
    const int* __restrict__ user, const int* __restrict__ item, const int* __restrict__ behavior,
    const float* __restrict__ ut, const float* __restrict__ itb, const float* __restrict__ bt,
    float* __restrict__ out)
{
    int gid = blockIdx.x * 256 + threadIdx.x;
    int r = gid >> 5;
    int m = gid & 31;
    if (r >= N_NODES) return;
    int s = off[r], e = off[r + 1];
    const float4* ut4 = (const float4*)ut;
    const float4* it4 = (const float4*)itb;
    const float4* bt4 = (const float4*)bt;
    float4 acc = {0.f, 0.f, 0.f, 0.f};
    for (int i = s; i < e; ++i) {
        int2 p = epack[i];
        int c = p.x;
        float v = __int_as_float(p.y);
        float4 a = ut4[(size_t)user[c] * 32 + m];
        float4 cc = it4[(size_t)item[c] * 32 + m];
        float4 d = bt4[(size_t)behavior[c] * 32 + m];
        a.x += cc.x + d.x; a.y += cc.y + d.y; a.z += cc.z + d.z; a.w += cc.w + d.w;
        fma4(acc, v, a);
    }
    ((float4*)out)[(size_t)r * 32 + m] = acc;
}

__global__ __launch_bounds__(256) void scatter_fused_kernel(
    const int* __restrict__ rows, const int* __restrict__ cols, const float* __restrict__ vals,
    const int* __restrict__ user, const int* __restrict__ item, const int* __restrict__ behavior,
    const float* __restrict__ ut, const float* __restrict__ itb, const float* __restrict__ bt,
    float* __restrict__ agg)
{
    int wave = (blockIdx.x * 256 + threadIdx.x) >> 6;
    int lane = threadIdx.x & 63;
    int e = wave * 2 + (lane >> 5);
    if (e >= N_EDGES) return;
    int r = rows[e];
    int c = cols[e];
    float v = vals[e];
    int m = lane & 31;
    const float4* ut4 = (const float4*)ut;
    const float4* it4 = (const float4*)itb;
    const float4* bt4 = (const float4*)bt;
    float4 a = ut4[(size_t)user[c] * 32 + m];
    float4 cc = it4[(size_t)item[c] * 32 + m];
    float4 d = bt4[(size_t)behavior[c] * 32 + m];
    a.x += cc.x + d.x; a.y += cc.y + d.y; a.z += cc.z + d.z; a.w += cc.w + d.w;
    float* o = agg + (size_t)r * DIM + m * 4;
    atomicAdd(o + 0, v * a.x);
    atomicAdd(o + 1, v * a.y);
    atomicAdd(o + 2, v * a.z);
    atomicAdd(o + 3, v * a.w);
}

// fallback GEMM: out[r] = agg[r] @ W^T + b, in-place f32 on io (verified R3)
__global__ __launch_bounds__(256) void gemm_mfma_kernel(
    const float* __restrict__ W, const float* __restrict__ bias, float* io)
{
    __shared__ unsigned short wlds[128 * 128];

    int tid = threadIdx.x;
    for (int c4 = tid; c4 < 128 * 128 / 4; c4 += 256) {
        float4 wv = ((const float4*)W)[c4];
        int i  = c4 >> 5;
        int k0 = (c4 & 31) * 4;
        int slot = (i >> 4) * 4 + (k0 >> 5);
        int lane = ((k0 & 31) >> 3) * 16 + (i & 15);
        ushort4 o;
        o.x = f2bf(wv.x); o.y = f2bf(wv.y); o.z = f2bf(wv.z); o.w = f2bf(wv.w);
        *(ushort4*)&wlds[slot * 512 + lane * 8 + (k0 & 7)] = o;
    }
    __syncthreads();

    int l = tid & 63;
    int w = tid >> 6;
    int c = l & 15;
    int g = l >> 4;
    int row = blockIdx.x * 64 + w * 16 + c;
    int rowc = row < N_NODES ? row : N_NODES - 1;

    const float4* a4 = (const float4*)io;
    bf16x8 bfrag[4];
    #pragma unroll
    for (int s = 0; s < 4; ++s) {
        float4 p0 = a4[(size_t)rowc * 32 + 8 * s + 2 * g];
        float4 p1 = a4[(size_t)rowc * 32 + 8 * s + 2 * g + 1];
        bf16x8 t;
        t[0] = (short)f2bf(p0.x); t[1] = (short)f2bf(p0.y);
        t[2] = (short)f2bf(p0.z); t[3] = (short)f2bf(p0.w);
        t[4] = (short)f2bf(p1.x); t[5] = (short)f2bf(p1.y);
        t[6] = (short)f2bf(p1.z); t[7] = (short)f2bf(p1.w);
        bfrag[s] = t;
    }

    f32x4 acc[8];
    #pragma unroll
    for (int ti = 0; ti < 8; ++ti) acc[ti] = (f32x4){0.f, 0.f, 0.f, 0.f};

    const bf16x8* wf = (const bf16x8*)wlds;
    #pragma unroll
    for (int ti = 0; ti < 8; ++ti) {
        #pragma unroll
        for (int s = 0; s < 4; ++s) {
            bf16x8 af = wf[(ti * 4 + s) * 64 + l];
            acc[ti] = __builtin_amdgcn_mfma_f32_16x16x32_bf16(af, bfrag[s], acc[ti], 0, 0, 0);
        }
    }

    if (row < N_NODES) {
        float4* orow = (float4*)(io + (size_t)row * DIM);
        const float4* b4 = (const float4*)bias;
        #pragma unroll
        for (int ti = 0; ti < 8; ++ti) {
            float4 bb = b4[ti * 4 + g];
            float4 o;
            o.x = acc[ti][0] + bb.x;
            o.y = acc[ti][1] + bb.y;
            o.z = acc[ti][2] + bb.z;
            o.w = acc[ti][3] + bb.w;
            orow[ti * 4 + g] = o;
        }
    }
}

extern "C" void kernel_launch(void* const* d_in, const int* in_sizes, int n_in,
                              void* d_out, int out_size, void* d_ws, size_t ws_size,
                              hipStream_t stream) {
    const int*   user           = (const int*)d_in[0];
    const int*   item           = (const int*)d_in[1];
    const int*   behavior       = (const int*)d_in[2];
    const int*   adj_rows       = (const int*)d_in[3];
    const int*   adj_cols       = (const int*)d_in[4];
    const float* adj_vals       = (const float*)d_in[5];
    const float* user_table     = (const float*)d_in[6];
    const float* item_table     = (const float*)d_in[7];
    const float* behavior_table = (const float*)d_in[8];
    const float* W              = (const float*)d_in[9];
    const float* b              = (const float*)d_in[10];
    float* out = (float*)d_out;

    const size_t Y_BYTES     = (size_t)N_NODES * DIM * sizeof(unsigned short); // 25,600,000
    const size_t CNT_BYTES   = (size_t)N_NODES * sizeof(int);                  // 400,000
    const size_t OFF_BYTES   = ((size_t)(N_NODES + 1) * sizeof(int) + 15) & ~(size_t)15;
    const size_t EPACK_BYTES = (size_t)N_EDGES * sizeof(int2);                 // 4,800,000
    const size_t BTW_BYTES   = 1024;
    const size_t WFRAG_BYTES = 128 * 128 * sizeof(unsigned short);             // 32,768

    const int edge_blocks = (N_EDGES + 255) / 256;
    const int agg_blocks  = (N_NODES * 16 + 255) / 256;  // 6250
    const int gemm_blocks = (N_NODES + 63) / 64;         // 1563 (fallback)

    char* ws = (char*)d_ws;
    const size_t need_full = Y_BYTES + CNT_BYTES + OFF_BYTES + EPACK_BYTES + BTW_BYTES + WFRAG_BYTES;
    const size_t need_csr  = CNT_BYTES + OFF_BYTES + EPACK_BYTES;

    if (ws_size >= need_full) {
        // UTW/ITW live in d_out (dead until agg fully overwrites it)
        unsigned short* utw = (unsigned short*)d_out;
        unsigned short* itw = utw + (size_t)N_NODES * DIM;
        size_t o = 0;
        unsigned short* y = (unsigned short*)(ws + o); o += Y_BYTES;
        int*  cnt   = (int*)(ws + o); o += CNT_BYTES;    // then fine cursor
        int*  off   = (int*)(ws + o); o += OFF_BYTES;
        int2* epack = (int2*)(ws + o); o += EPACK_BYTES;
        unsigned short* btw = (unsigned short*)(ws + o); o += BTW_BYTES;
        unsigned short* wfrag = (unsigned short*)(ws + o);
        int*  bsum  = (int*)epack;   // epack[0..97] dead until kB-bucket; stream-ordered

        hipMemsetAsync(cnt, 0, CNT_BYTES, stream);
        wconv_kernel<<<16, 256, 0, stream>>>(W, wfrag);
        ka_kernel<<<2 * TCONV_B + 1 + HIST_B, 256, 0, stream>>>(
            adj_rows, cnt, user_table, item_table, behavior_table,
            (const bf16x8*)wfrag, utw, itw, btw);
        scan1_kernel<<<SCAN_BLOCKS, 256, 0, stream>>>(cnt, off, bsum);
        scan3_kernel<<<SCAN_BLOCKS, 256, 0, stream>>>(bsum, off, cnt);
        kb_kernel<<<BUCKET_B + COMBINE_B, 256, 0, stream>>>(
            adj_rows, adj_cols, adj_vals, cnt, epack,
            user, item, behavior, utw, itw, btw, y);
        agg_bias_kernel<<<agg_blocks, 256, 0, stream>>>(off, epack, y, b, out);
    } else if (ws_size >= need_csr) {
        int*  cnt   = (int*)ws;
        int*  off   = (int*)(ws + CNT_BYTES);
        int2* epack = (int2*)(ws + CNT_BYTES + OFF_BYTES);
        int*  bsum  = (int*)epack;

        hipMemsetAsync(cnt, 0, CNT_BYTES, stream);
        hist_kernel<<<edge_blocks, 256, 0, stream>>>(adj_rows, cnt);
        scan1_kernel<<<SCAN_BLOCKS, 256, 0, stream>>>(cnt, off, bsum);
        scan3_kernel<<<SCAN_BLOCKS, 256, 0, stream>>>(bsum, off, cnt);
        bucket_kernel<<<edge_blocks, 256, 0, stream>>>(
            adj_rows, adj_cols, adj_vals, cnt, epack);
        agg_fused_kernel<<<(N_NODES * 32 + 255) / 256, 256, 0, stream>>>(
            off, epack, user, item, behavior,
            user_table, item_table, behavior_table, out);
        gemm_mfma_kernel<<<gemm_blocks, 256, 0, stream>>>(W, b, out);
    } else {
        hipMemsetAsync(d_out, 0, (size_t)N_NODES * DIM * sizeof(float), stream);
        const int scatter_blocks = (N_EDGES / 2 * 64 + 255) / 256;
        scatter_fused_kernel<<<scatter_blocks, 256, 0, stream>>>(
            adj_rows, adj_cols, adj_vals, user, item, behavior,
            user_table, item_table, behavior_table, out);
        gemm_mfma_kernel<<<gemm_blocks, 256, 0, stream>>>(W, b, out);
    }
}

// Round 17
// 132.800 us; speedup vs baseline: 1.6699x; 1.1342x over previous
//
#include <hip/hip_runtime.h>

#define N_NODES 100000
#define N_EDGES 600000
#define DIM 128

#define N4 (N_NODES / 4)
#define SCAN_BLOCKS ((N_NODES + 1023) / 1024)   // 98

// K1 mega-kernel block partition
#define EMBED_B 1563      // 25008 groups of 16 lanes; each group pipelines 4 rows
#define HIST_B  2344      // ceil(600000/256)
#define WCONV_B 16
#define NGROUP  25000     // row stride for the embed loop
// K4 mega-kernel partition: XCD-partitioned bucket first, then gemm
#define NPART    8
#define CHUNKS   ((N_EDGES + 1023) / 1024)      // 586
#define BUCKET_B (CHUNKS * NPART)               // 4688
#define GEMM_B   1563                           // one 64-row tile per block (no LDS)
#define PART_SZ  (N_NODES / NPART)              // 12500

typedef __attribute__((ext_vector_type(8))) short bf16x8;
typedef __attribute__((ext_vector_type(4))) float f32x4;

__device__ __forceinline__ void fma4(float4& acc, float s, const float4 w) {
    acc.x = fmaf(s, w.x, acc.x);
    acc.y = fmaf(s, w.y, acc.y);
    acc.z = fmaf(s, w.z, acc.z);
    acc.w = fmaf(s, w.w, acc.w);
}

__device__ __forceinline__ unsigned short f2bf(float f) {
    union { float f; unsigned int u; } v; v.f = f;
    unsigned int r = v.u + 0x7fffu + ((v.u >> 16) & 1u);   // RNE
    return (unsigned short)(r >> 16);
}

__device__ __forceinline__ float bf2f(unsigned short u) {
    union { unsigned int i; float f; } v;
    v.i = ((unsigned int)u) << 16;
    return v.f;
}

// ---------------- K1: embed(2-deep gather pipe)->bf16 || hist || wconv ----------------
__global__ __launch_bounds__(256) void k1_kernel(
    const int* __restrict__ user, const int* __restrict__ item, const int* __restrict__ behavior,
    const float* __restrict__ ut, const float* __restrict__ itb, const float* __restrict__ bt,
    const int* __restrict__ rows, const float* __restrict__ W,
    unsigned short* __restrict__ x16, int* __restrict__ cnt, unsigned short* __restrict__ wfrag)
{
    int b = blockIdx.x;
    int t = threadIdx.x;
    if (b < EMBED_B) {
        int gid = b * 256 + t;
        int g = gid >> 4;
        int m = gid & 15;
        if (g < NGROUP) {
            const float4* ut4 = (const float4*)ut;
            const float4* it4 = (const float4*)itb;
            const float4* bt4 = (const float4*)bt;
            int u0 = user[g],              i0 = item[g],              h0 = behavior[g];
            int u1 = user[g + NGROUP],     i1 = item[g + NGROUP],     h1 = behavior[g + NGROUP];
            int u2 = user[g + 2 * NGROUP], i2 = item[g + 2 * NGROUP], h2 = behavior[g + 2 * NGROUP];
            int u3 = user[g + 3 * NGROUP], i3 = item[g + 3 * NGROUP], h3 = behavior[g + 3 * NGROUP];

            #define GATHER(A0,A1,C0,C1,D0,D1,u,iv,bh)                     \
                float4 A0 = ut4[(size_t)(u)  * 32 + 2 * m];               \
                float4 A1 = ut4[(size_t)(u)  * 32 + 2 * m + 1];           \
                float4 C0 = it4[(size_t)(iv) * 32 + 2 * m];               \
                float4 C1 = it4[(size_t)(iv) * 32 + 2 * m + 1];           \
                float4 D0 = bt4[(size_t)(bh) * 32 + 2 * m];               \
                float4 D1 = bt4[(size_t)(bh) * 32 + 2 * m + 1];

            #define CONVST(r,A0,A1,C0,C1,D0,D1)                           \
                {                                                         \
                    ushort4 o0, o1;                                       \
                    o0.x = f2bf(A0.x + C0.x + D0.x);                      \
                    o0.y = f2bf(A0.y + C0.y + D0.y);                      \
                    o0.z = f2bf(A0.z + C0.z + D0.z);                      \
                    o0.w = f2bf(A0.w + C0.w + D0.w);                      \
                    o1.x = f2bf(A1.x + C1.x + D1.x);                      \
                    o1.y = f2bf(A1.y + C1.y + D1.y);                      \
                    o1.z = f2bf(A1.z + C1.z + D1.z);                      \
                    o1.w = f2bf(A1.w + C1.w + D1.w);                      \
                    unsigned short* xr = x16 + (size_t)(r) * DIM + 8 * m; \
                    *(ushort4*)xr       = o0;                             \
                    *(ushort4*)(xr + 4) = o1;                             \
                }

            GATHER(a0A,a1A,c0A,c1A,d0A,d1A, u0, i0, h0)
            GATHER(a0B,a1B,c0B,c1B,d0B,d1B, u1, i1, h1)
            CONVST(g,              a0A,a1A,c0A,c1A,d0A,d1A)
            GATHER(a0C,a1C,c0C,c1C,d0C,d1C, u2, i2, h2)
            CONVST(g + NGROUP,     a0B,a1B,c0B,c1B,d0B,d1B)
            GATHER(a0D,a1D,c0D,c1D,d0D,d1D, u3, i3, h3)
            CONVST(g + 2 * NGROUP, a0C,a1C,c0C,c1C,d0C,d1C)
            CONVST(g + 3 * NGROUP, a0D,a1D,c0D,c1D,d0D,d1D)
            #undef GATHER
            #undef CONVST
        }
    } else if (b < EMBED_B + HIST_B) {
        int e = (b - EMBED_B) * 256 + t;
        if (e < N_EDGES) atomicAdd(&cnt[rows[e]], 1);
    } else {
        int c4 = (b - EMBED_B - HIST_B) * 256 + t;
        if (c4 < 128 * 128 / 4) {
            float4 wv = ((const float4*)W)[c4];
            int i  = c4 >> 5;            // W row (out col)
            int k0 = (c4 & 31) * 4;      // W col (k)
            int slot = (i >> 4) * 4 + (k0 >> 5);
            int lane = ((k0 & 31) >> 3) * 16 + (i & 15);
            ushort4 o;
            o.x = f2bf(wv.x); o.y = f2bf(wv.y); o.z = f2bf(wv.z); o.w = f2bf(wv.w);
            *(ushort4*)&wfrag[slot * 512 + lane * 8 + (k0 & 7)] = o;
        }
    }
}

// scan level 1
__global__ __launch_bounds__(256) void scan1_kernel(
    const int* __restrict__ cnt, int* __restrict__ off, int* __restrict__ bsum)
{
    __shared__ int s[256];
    int t = threadIdx.x;
    int b = blockIdx.x;
    int i4 = b * 256 + t;
    int4 c = {0, 0, 0, 0};
    if (i4 < N4) c = ((const int4*)cnt)[i4];
    int tsum = c.x + c.y + c.z + c.w;
    s[t] = tsum;
    __syncthreads();
    for (int d = 1; d < 256; d <<= 1) {
        int v = (t >= d) ? s[t - d] : 0;
        __syncthreads();
        s[t] += v;
        __syncthreads();
    }
    int texcl = s[t] - tsum;
    if (t == 255) bsum[b] = s[255];
    if (i4 < N4) {
        int4 o;
        o.x = texcl;
        o.y = o.x + c.x;
        o.z = o.y + c.y;
        o.w = o.z + c.z;
        ((int4*)off)[i4] = o;
    }
}

// scan level 2+3
__global__ __launch_bounds__(256) void scan3_kernel(
    const int* __restrict__ bsum, int* __restrict__ off, int* __restrict__ cur)
{
    __shared__ int s[256];
    int t = threadIdx.x;
    int b = blockIdx.x;
    s[t] = (t < b && t < SCAN_BLOCKS) ? bsum[t] : 0;
    __syncthreads();
    for (int d = 1; d < 256; d <<= 1) {
        int v = (t >= d) ? s[t - d] : 0;
        __syncthreads();
        s[t] += v;
        __syncthreads();
    }
    int base = s[255];
    int i4 = b * 256 + t;
    if (i4 < N4) {
        int4 o = ((const int4*)off)[i4];
        o.x += base; o.y += base; o.z += base; o.w += base;
        ((int4*)off)[i4] = o;
        ((int4*)cur)[i4] = o;
    }
    if (b == 0 && t == 0) off[N_NODES] = N_EDGES;
}

// ---------------- K4: XCD-partitioned bucket || gemm (in-place, NO LDS) ----------------
// Bucket (R14-verified): block b handles edge-chunk b>>3, scatters only rows
// in partition b&7 -> all writers of an epack line on one XCD, L2 merges.
// GEMM: wfrag from global (L1-resident), one 64-row tile per block.
// Swapped-operand MFMA (verified R3+): C/D j = lane&15 (row), i = 16ti+4g+q.
__global__ __launch_bounds__(256) void k4_kernel(
    const bf16x8* __restrict__ wf, unsigned short* xy,
    const int* __restrict__ rows, const int* __restrict__ cols, const float* __restrict__ vals,
    int* __restrict__ cur, int2* __restrict__ epack)
{
    int b = blockIdx.x;
    int t = threadIdx.x;
    if (b < BUCKET_B) {
        int p = b & (NPART - 1);
        int chunk = b >> 3;
        int base = chunk * 1024;
        #pragma unroll
        for (int j = 0; j < 4; ++j) {
            int e = base + t + j * 256;
            if (e < N_EDGES) {
                int r = rows[e];
                int c = cols[e];
                float v = vals[e];
                if (r / PART_SZ == p) {
                    int slot = atomicAdd(&cur[r], 1);
                    int2 pk;
                    pk.x = c;
                    pk.y = __float_as_int(v);
                    epack[slot] = pk;
                }
            }
        }
    } else {
        int b2 = b - BUCKET_B;
        int l = t & 63;
        int w = t >> 6;
        int c = l & 15;
        int g = l >> 4;
        int row = b2 * 64 + w * 16 + c;
        int rowc = row < N_NODES ? row : N_NODES - 1;
        const bf16x8* xr = (const bf16x8*)(xy + (size_t)rowc * DIM);
        bf16x8 bfrag[4];
        #pragma unroll
        for (int s = 0; s < 4; ++s) bfrag[s] = xr[g + 4 * s];

        f32x4 acc[8];
        #pragma unroll
        for (int ti = 0; ti < 8; ++ti) acc[ti] = (f32x4){0.f, 0.f, 0.f, 0.f};

        #pragma unroll
        for (int ti = 0; ti < 8; ++ti) {
            #pragma unroll
            for (int s = 0; s < 4; ++s) {
                bf16x8 af = wf[(ti * 4 + s) * 64 + l];
                acc[ti] = __builtin_amdgcn_mfma_f32_16x16x32_bf16(af, bfrag[s], acc[ti], 0, 0, 0);
            }
        }

        if (row < N_NODES) {
            unsigned short* yr = xy + (size_t)row * DIM;
            #pragma unroll
            for (int ti = 0; ti < 8; ++ti) {
                ushort4 o;
                o.x = f2bf(acc[ti][0]);
                o.y = f2bf(acc[ti][1]);
                o.z = f2bf(acc[ti][2]);
                o.w = f2bf(acc[ti][3]);
                *(ushort4*)(yr + 16 * ti + 4 * g) = o;
            }
        }
    }
}

// K_B: out[r] = b + sum_{e in row r} val[e] * y[col[e]]   (y bf16, acc f32)
__global__ __launch_bounds__(256) void agg_bias_kernel(
    const int* __restrict__ off, const int2* __restrict__ epack,
    const unsigned short* __restrict__ y, const float* __restrict__ bias,
    float* __restrict__ out)
{
    int gid = blockIdx.x * 256 + threadIdx.x;
    int r = gid >> 4;
    int m = gid & 15;
    if (r >= N_NODES) return;
    int s = off[r], e = off[r + 1];
    const bf16x8* y8 = (const bf16x8*)y;   // index = node*16 + m

    float a0[8], a1[8], a2[8], a3[8];
    #pragma unroll
    for (int j = 0; j < 8; ++j) { a0[j] = 0.f; a1[j] = 0.f; a2[j] = 0.f; a3[j] = 0.f; }

    int i = s;
    for (; i + 3 < e; i += 4) {
        int2 p0 = epack[i];
        int2 p1 = epack[i + 1];
        int2 p2 = epack[i + 2];
        int2 p3 = epack[i + 3];
        bf16x8 y0 = y8[(size_t)p0.x * 16 + m];
        bf16x8 y1 = y8[(size_t)p1.x * 16 + m];
        bf16x8 y2 = y8[(size_t)p2.x * 16 + m];
        bf16x8 y3 = y8[(size_t)p3.x * 16 + m];
        float v0 = __int_as_float(p0.y);
        float v1 = __int_as_float(p1.y);
        float v2 = __int_as_float(p2.y);
        float v3 = __int_as_float(p3.y);
        #pragma unroll
        for (int j = 0; j < 8; ++j) {
            a0[j] = fmaf(v0, bf2f((unsigned short)y0[j]), a0[j]);
            a1[j] = fmaf(v1, bf2f((unsigned short)y1[j]), a1[j]);
            a2[j] = fmaf(v2, bf2f((unsigned short)y2[j]), a2[j]);
            a3[j] = fmaf(v3, bf2f((unsigned short)y3[j]), a3[j]);
        }
    }
    for (; i < e; ++i) {
        int2 p0 = epack[i];
        float v0 = __int_as_float(p0.y);
        bf16x8 y0 = y8[(size_t)p0.x * 16 + m];
        #pragma unroll
        for (int j = 0; j < 8; ++j)
            a0[j] = fmaf(v0, bf2f((unsigned short)y0[j]), a0[j]);
    }

    const float4* b4 = (const float4*)bias;
    float4 bb0 = b4[2 * m], bb1 = b4[2 * m + 1];
    float4 o0, o1;
    o0.x = a0[0] + a1[0] + a2[0] + a3[0] + bb0.x;
    o0.y = a0[1] + a1[1] + a2[1] + a3[1] + bb0.y;
    o0.z = a0[2] + a1[2] + a2[2] + a3[2] + bb0.z;
    o0.w = a0[3] + a1[3] + a2[3] + a3[3] + bb0.w;
    o1.x = a0[4] + a1[4] + a2[4] + a3[4] + bb1.x;
    o1.y = a0[5] + a1[5] + a2[5] + a3[5] + bb1.y;
    o1.z = a0[6] + a1[6] + a2[6] + a3[6] + bb1.z;
    o1.w = a0[7] + a1[7] + a2[7] + a3[7] + bb1.w;
    float4* orow = (float4*)(out + (size_t)r * DIM);
    orow[2 * m]     = o0;
    orow[2 * m + 1] = o1;
}

// ---- fallback path kernels (mid / tiny ws) ----

__global__ __launch_bounds__(256) void hist_kernel(
    const int* __restrict__ rows, int* __restrict__ cnt)
{
    int e = blockIdx.x * 256 + threadIdx.x;
    if (e >= N_EDGES) return;
    atomicAdd(&cnt[rows[e]], 1);
}

__global__ __launch_bounds__(256) void bucket_kernel(
    const int* __restrict__ rows, const int* __restrict__ cols, const float* __restrict__ vals,
    int* __restrict__ cur, int2* __restrict__ epack)
{
    int e = blockIdx.x * 256 + threadIdx.x;
    if (e >= N_EDGES) return;
    int r = rows[e];
    int slot = atomicAdd(&cur[r], 1);
    int2 p;
    p.x = cols[e];
    p.y = __float_as_int(vals[e]);
    epack[slot] = p;
}

__global__ __launch_bounds__(256) void agg_fused_kernel(
    const int* __restrict__ off, const int2* __restrict__ epack,
    const int* __restrict__ user, const int* __restrict__ item, const int* __restrict__ behavior,
    const float* __restrict__ ut, const float* __restrict__ itb, const float* __restrict__ bt,
    float* __restrict__ out)
{
    int gid = blockIdx.x * 256 + threadIdx.x;
    int r = gid >> 5;
    int m = gid & 31;
    if (r >= N_NODES) return;
    int s = off[r], e = off[r + 1];
    const float4* ut4 = (const float4*)ut;
    const float4* it4 = (const float4*)itb;
    const float4* bt4 = (const float4*)bt;
    float4 acc = {0.f, 0.f, 0.f, 0.f};
    for (int i = s; i < e; ++i) {
        int2 p = epack[i];
        int c = p.x;
        float v = __int_as_float(p.y);
        float4 a = ut4[(size_t)user[c] * 32 + m];
        float4 cc = it4[(size_t)item[c] * 32 + m];
        float4 d = bt4[(size_t)behavior[c] * 32 + m];
        a.x += cc.x + d.x; a.y += cc.y + d.y; a.z += cc.z + d.z; a.w += cc.w + d.w;
        fma4(acc, v, a);
    }
    ((float4*)out)[(size_t)r * 32 + m] = acc;
}

__global__ __launch_bounds__(256) void scatter_fused_kernel(
    const int* __restrict__ rows, const int* __restrict__ cols, const float* __restrict__ vals,
    const int* __restrict__ user, const int* __restrict__ item, const int* __restrict__ behavior,
    const float* __restrict__ ut, const float* __restrict__ itb, const float* __restrict__ bt,
    float* __restrict__ agg)
{
    int wave = (blockIdx.x * 256 + threadIdx.x) >> 6;
    int lane = threadIdx.x & 63;
    int e = wave * 2 + (lane >> 5);
    if (e >= N_EDGES) return;
    int r = rows[e];
    int c = cols[e];
    float v = vals[e];
    int m = lane & 31;
    const float4* ut4 = (const float4*)ut;
    const float4* it4 = (const float4*)itb;
    const float4* bt4 = (const float4*)bt;
    float4 a = ut4[(size_t)user[c] * 32 + m];
    float4 cc = it4[(size_t)item[c] * 32 + m];
    float4 d = bt4[(size_t)behavior[c] * 32 + m];
    a.x += cc.x + d.x; a.y += cc.y + d.y; a.z += cc.z + d.z; a.w += cc.w + d.w;
    float* o = agg + (size_t)r * DIM + m * 4;
    atomicAdd(o + 0, v * a.x);
    atomicAdd(o + 1, v * a.y);
    atomicAdd(o + 2, v * a.z);
    atomicAdd(o + 3, v * a.w);
}

// fallback GEMM: out[r] = agg[r] @ W^T + b, in-place f32 on io (verified R3)
__global__ __launch_bounds__(256) void gemm_mfma_kernel(
    const float* __restrict__ W, const float* __restrict__ bias, float* io)
{
    __shared__ unsigned short wlds[128 * 128];

    int tid = threadIdx.x;
    for (int c4 = tid; c4 < 128 * 128 / 4; c4 += 256) {
        float4 wv = ((const float4*)W)[c4];
        int i  = c4 >> 5;
        int k0 = (c4 & 31) * 4;
        int slot = (i >> 4) * 4 + (k0 >> 5);
        int lane = ((k0 & 31) >> 3) * 16 + (i & 15);
        ushort4 o;
        o.x = f2bf(wv.x); o.y = f2bf(wv.y); o.z = f2bf(wv.z); o.w = f2bf(wv.w);
        *(ushort4*)&wlds[slot * 512 + lane * 8 + (k0 & 7)] = o;
    }
    __syncthreads();

    int l = tid & 63;
    int w = tid >> 6;
    int c = l & 15;
    int g = l >> 4;
    int row = blockIdx.x * 64 + w * 16 + c;
    int rowc = row < N_NODES ? row : N_NODES - 1;

    const float4* a4 = (const float4*)io;
    bf16x8 bfrag[4];
    #pragma unroll
    for (int s = 0; s < 4; ++s) {
        float4 p0 = a4[(size_t)rowc * 32 + 8 * s + 2 * g];
        float4 p1 = a4[(size_t)rowc * 32 + 8 * s + 2 * g + 1];
        bf16x8 t;
        t[0] = (short)f2bf(p0.x); t[1] = (short)f2bf(p0.y);
        t[2] = (short)f2bf(p0.z); t[3] = (short)f2bf(p0.w);
        t[4] = (short)f2bf(p1.x); t[5] = (short)f2bf(p1.y);
        t[6] = (short)f2bf(p1.z); t[7] = (short)f2bf(p1.w);
        bfrag[s] = t;
    }

    f32x4 acc[8];
    #pragma unroll
    for (int ti = 0; ti < 8; ++ti) acc[ti] = (f32x4){0.f, 0.f, 0.f, 0.f};

    const bf16x8* wf = (const bf16x8*)wlds;
    #pragma unroll
    for (int ti = 0; ti < 8; ++ti) {
        #pragma unroll
        for (int s = 0; s < 4; ++s) {
            bf16x8 af = wf[(ti * 4 + s) * 64 + l];
            acc[ti] = __builtin_amdgcn_mfma_f32_16x16x32_bf16(af, bfrag[s], acc[ti], 0, 0, 0);
        }
    }

    if (row < N_NODES) {
        float4* orow = (float4*)(io + (size_t)row * DIM);
        const float4* b4 = (const float4*)bias;
        #pragma unroll
        for (int ti = 0; ti < 8; ++ti) {
            float4 bb = b4[ti * 4 + g];
            float4 o;
            o.x = acc[ti][0] + bb.x;
            o.y = acc[ti][1] + bb.y;
            o.z = acc[ti][2] + bb.z;
            o.w = acc[ti][3] + bb.w;
            orow[ti * 4 + g] = o;
        }
    }
}

extern "C" void kernel_launch(void* const* d_in, const int* in_sizes, int n_in,
                              void* d_out, int out_size, void* d_ws, size_t ws_size,
                              hipStream_t stream) {
    const int*   user           = (const int*)d_in[0];
    const int*   item           = (const int*)d_in[1];
    const int*   behavior       = (const int*)d_in[2];
    const int*   adj_rows       = (const int*)d_in[3];
    const int*   adj_cols       = (const int*)d_in[4];
    const float* adj_vals       = (const float*)d_in[5];
    const float* user_table     = (const float*)d_in[6];
    const float* item_table     = (const float*)d_in[7];
    const float* behavior_table = (const float*)d_in[8];
    const float* W              = (const float*)d_in[9];
    const float* b              = (const float*)d_in[10];
    float* out = (float*)d_out;

    const size_t X16_BYTES   = (size_t)N_NODES * DIM * sizeof(unsigned short); // 25,600,000
    const size_t CNT_BYTES   = (size_t)N_NODES * sizeof(int);                  // 400,000
    const size_t OFF_BYTES   = ((size_t)(N_NODES + 1) * sizeof(int) + 15) & ~(size_t)15;
    const size_t EPACK_BYTES = (size_t)N_EDGES * sizeof(int2);                 // 4,800,000
    const size_t WFRAG_BYTES = 128 * 128 * sizeof(unsigned short);             // 32,768

    const int edge_blocks = (N_EDGES + 255) / 256;
    const int agg_blocks  = (N_NODES * 16 + 255) / 256;  // 6250
    const int gemm_blocks = (N_NODES + 63) / 64;         // 1563 (fallback)

    char* ws = (char*)d_ws;
    const size_t need_full = X16_BYTES + CNT_BYTES + OFF_BYTES + EPACK_BYTES + WFRAG_BYTES;
    const size_t need_csr  = CNT_BYTES + OFF_BYTES + EPACK_BYTES;

    if (ws_size >= need_full) {
        size_t o = 0;
        unsigned short* x16 = (unsigned short*)(ws + o); o += X16_BYTES;   // becomes y in-place
        int*  cnt   = (int*)(ws + o); o += CNT_BYTES;                      // then fine cursor
        int*  off   = (int*)(ws + o); o += OFF_BYTES;
        int2* epack = (int2*)(ws + o); o += EPACK_BYTES;
        unsigned short* wfrag = (unsigned short*)(ws + o);
        int*  bsum  = (int*)epack;   // epack[0..97] dead until k4-bucket; stream-ordered

        hipMemsetAsync(cnt, 0, CNT_BYTES, stream);
        k1_kernel<<<EMBED_B + HIST_B + WCONV_B, 256, 0, stream>>>(
            user, item, behavior, user_table, item_table, behavior_table,
            adj_rows, W, x16, cnt, wfrag);
        scan1_kernel<<<SCAN_BLOCKS, 256, 0, stream>>>(cnt, off, bsum);
        scan3_kernel<<<SCAN_BLOCKS, 256, 0, stream>>>(bsum, off, cnt);
        k4_kernel<<<BUCKET_B + GEMM_B, 256, 0, stream>>>(
            (const bf16x8*)wfrag, x16, adj_rows, adj_cols, adj_vals, cnt, epack);
        agg_bias_kernel<<<agg_blocks, 256, 0, stream>>>(off, epack, x16, b, out);
    } else if (ws_size >= need_csr) {
        int*  cnt   = (int*)ws;
        int*  off   = (int*)(ws + CNT_BYTES);
        int2* epack = (int2*)(ws + CNT_BYTES + OFF_BYTES);
        int*  bsum  = (int*)epack;

        hipMemsetAsync(cnt, 0, CNT_BYTES, stream);
        hist_kernel<<<edge_blocks, 256, 0, stream>>>(adj_rows, cnt);
        scan1_kernel<<<SCAN_BLOCKS, 256, 0, stream>>>(cnt, off, bsum);
        scan3_kernel<<<SCAN_BLOCKS, 256, 0, stream>>>(bsum, off, cnt);
        bucket_kernel<<<edge_blocks, 256, 0, stream>>>(
            adj_rows, adj_cols, adj_vals, cnt, epack);
        agg_fused_kernel<<<(N_NODES * 32 + 255) / 256, 256, 0, stream>>>(
            off, epack, user, item, behavior,
            user_table, item_table, behavior_table, out);
        gemm_mfma_kernel<<<gemm_blocks, 256, 0, stream>>>(W, b, out);
    } else {
        hipMemsetAsync(d_out, 0, (size_t)N_NODES * DIM * sizeof(float), stream);
        const int scatter_blocks = (N_EDGES / 2 * 64 + 255) / 256;
        scatter_fused_kernel<<<scatter_blocks, 256, 0, stream>>>(
            adj_rows, adj_cols, adj_vals, user, item, behavior,
            user_table, item_table, behavior_table, out);
        gemm_mfma_kernel<<<gemm_blocks, 256, 0, stream>>>(W, b, out);
    }
}